// Round 2
// baseline (505.978 us; speedup 1.0000x reference)
//
#include <hip/hip_runtime.h>
#include <hip/hip_bf16.h>

// Problem constants (B,R,M,L,H) = (256, 2048, 65536, 64, 4)
#define BB   256
#define RR   2048
#define MM   65536
#define LL   64
#define HH   4
#define NROW (BB*HH)   // 1024 (b,h) rows
#define KEYS (HH*LL)   // 256 key outputs per batch
#define MROWS 16       // rows per block in main kernels
#define MTILE 1024     // m-slots per block (256 thr * float4)

typedef float f4v __attribute__((ext_vector_type(4)));

// ---------------- generic 64x64 tiled transpose: out[c][r] = in[r][c] ----------------
__global__ __launch_bounds__(256) void transpose_k(const float* __restrict__ in,
                                                   float* __restrict__ out,
                                                   int NR, int NC) {
    __shared__ float t[64 * 65];
    int r0 = blockIdx.x * 64, c0 = blockIdx.y * 64;
    int lane = threadIdx.x & 63, w = threadIdx.x >> 6;
#pragma unroll
    for (int i = 0; i < 16; ++i) {
        int rr = i * 4 + w;
        t[lane * 65 + rr] = in[(size_t)(r0 + rr) * NC + c0 + lane];
    }
    __syncthreads();
#pragma unroll
    for (int i = 0; i < 16; ++i) {
        int cc = i * 4 + w;
        out[(size_t)(c0 + cc) * NR + r0 + lane] = t[cc * 65 + lane];
    }
}

// ---------------- K0: split-k partial keys GEMM: kpart[kc][b][j] = sum_k S[b][k]*WkT[k][j] ----
__global__ __launch_bounds__(256) void k0_keys(const float* __restrict__ S,
                                               const float* __restrict__ WkT,
                                               float* __restrict__ kpart) {
    __shared__ float sl[8 * 256];
    int bg  = blockIdx.x;   // 0..31, 8 batches each
    int kc  = blockIdx.y;   // 0..7, 256 k each
    int tid = threadIdx.x;
    int b0  = bg * 8;
#pragma unroll
    for (int bi = 0; bi < 8; ++bi)
        sl[bi * 256 + tid] = S[(size_t)(b0 + bi) * RR + kc * 256 + tid];
    __syncthreads();
    float acc[8] = {0, 0, 0, 0, 0, 0, 0, 0};
    const float* wp = WkT + (size_t)kc * 256 * KEYS + tid;
#pragma unroll 4
    for (int kk = 0; kk < 256; ++kk) {
        float wv = wp[kk * KEYS];
#pragma unroll
        for (int bi = 0; bi < 8; ++bi)
            acc[bi] = fmaf(sl[bi * 256 + kk], wv, acc[bi]);
    }
    float* op = kpart + (size_t)kc * BB * KEYS + (size_t)b0 * KEYS + tid;
#pragma unroll
    for (int bi = 0; bi < 8; ++bi)
        op[bi * KEYS] = acc[bi];
}

// ---------------- K1: per-(b,h): beta, key-norm, write qT[l][bh] = keys*beta/norm ----------
__global__ __launch_bounds__(256) void k1_finalize(const float* __restrict__ S,
                                                   const float* __restrict__ kpart,
                                                   const float* __restrict__ bk,
                                                   const float* __restrict__ Wb,
                                                   const float* __restrict__ bb,
                                                   float* __restrict__ qT) {
    int bh = blockIdx.x, b = bh >> 2, h = bh & 3;
    int tid = threadIdx.x, lane = tid & 63, w = tid >> 6;
    // beta = relu(S[b]·Wb[h] + bb[h]) via block reduction
    float p = 0.f;
#pragma unroll
    for (int i = 0; i < 8; ++i) {
        int k = i * 256 + tid;
        p += S[(size_t)b * RR + k] * Wb[(size_t)h * RR + k];
    }
#pragma unroll
    for (int off = 32; off > 0; off >>= 1) p += __shfl_down(p, off, 64);
    __shared__ float red[4];
    if (lane == 0) red[w] = p;
    __syncthreads();
    if (tid < 64) {
        float beta = red[0] + red[1] + red[2] + red[3] + bb[h];
        beta = beta > 0.f ? beta : 0.f;
        int l = lane;
        float kv = bk[h * LL + l];
#pragma unroll
        for (int c = 0; c < 8; ++c)
            kv += kpart[(size_t)c * BB * KEYS + (size_t)b * KEYS + h * LL + l];
        float sq = kv * kv;
#pragma unroll
        for (int off = 1; off < 64; off <<= 1) sq += __shfl_xor(sq, off, 64);
        float scale = beta / sqrtf(sq);
        qT[(size_t)l * NROW + bh] = kv * scale;
    }
}

// ---- stage q[l=0..63][r=0..15] for this row-group into LDS (4 KB), conflict-free ----
__device__ __forceinline__ void stage_q(const float* __restrict__ qT, int r0,
                                        float* __restrict__ qs, int tid) {
#pragma unroll
    for (int i = 0; i < 4; ++i) {
        int idx = i * 256 + tid;           // 0..1023
        int l = idx >> 4, r = idx & 15;
        qs[idx] = qT[(size_t)l * NROW + r0 + r];
    }
}

// ---------------- K2: per (row-group, m-tile): per-wave partial max & sumexp -----------
__global__ __launch_bounds__(256) void k2_partial(const float* __restrict__ memT,
                                                  const float* __restrict__ qT,
                                                  float* __restrict__ pmax,
                                                  float* __restrict__ psum) {
    __shared__ float qs[LL * MROWS];       // [l][r], 4 KB
    int bx = blockIdx.x;
    int mtile = bx >> 6, rg = bx & 63;
    int r0 = rg * MROWS;
    int tid = threadIdx.x, lane = tid & 63, w = tid >> 6;
    int m = mtile * MTILE + tid * 4;
    stage_q(qT, r0, qs, tid);
    __syncthreads();
    const float* mp = memT + m;
    float acc[MROWS][4];
#pragma unroll
    for (int r = 0; r < MROWS; ++r)
        acc[r][0] = acc[r][1] = acc[r][2] = acc[r][3] = 0.f;
#pragma unroll 4
    for (int l = 0; l < LL; ++l) {
        float4 v = *(const float4*)(mp + (size_t)l * MM);
        const f4v* qrow = (const f4v*)(qs + l * MROWS);
#pragma unroll
        for (int rq = 0; rq < MROWS / 4; ++rq) {
            f4v q4 = qrow[rq];             // ds_read_b128, broadcast
#pragma unroll
            for (int j = 0; j < 4; ++j) {
                int r = rq * 4 + j;
                float qv = q4[j];
                acc[r][0] = fmaf(qv, v.x, acc[r][0]);
                acc[r][1] = fmaf(qv, v.y, acc[r][1]);
                acc[r][2] = fmaf(qv, v.z, acc[r][2]);
                acc[r][3] = fmaf(qv, v.w, acc[r][3]);
            }
        }
    }
    int col = mtile * 4 + w;  // 256 per-wave partials per row
#pragma unroll
    for (int r = 0; r < MROWS; ++r) {
        float mx = fmaxf(fmaxf(acc[r][0], acc[r][1]), fmaxf(acc[r][2], acc[r][3]));
#pragma unroll
        for (int off = 1; off < 64; off <<= 1) mx = fmaxf(mx, __shfl_xor(mx, off, 64));
        float s = __expf(acc[r][0] - mx) + __expf(acc[r][1] - mx)
                + __expf(acc[r][2] - mx) + __expf(acc[r][3] - mx);
#pragma unroll
        for (int off = 1; off < 64; off <<= 1) s += __shfl_xor(s, off, 64);
        if (lane == 0) {
            pmax[(size_t)(r0 + r) * 256 + col] = mx;
            psum[(size_t)(r0 + r) * 256 + col] = s;
        }
    }
}

// ---------------- K3: combine 256 per-wave partials per row -> (gmax, 1/gsum) ---------
__global__ __launch_bounds__(256) void k3_combine(const float* __restrict__ pmax,
                                                  const float* __restrict__ psum,
                                                  float* __restrict__ rstat) {
    int row = blockIdx.x, tid = threadIdx.x, lane = tid & 63, w = tid >> 6;
    float my_max = pmax[(size_t)row * 256 + tid];
    float my_sum = psum[(size_t)row * 256 + tid];
    float mx = my_max;
#pragma unroll
    for (int off = 1; off < 64; off <<= 1) mx = fmaxf(mx, __shfl_xor(mx, off, 64));
    __shared__ float wm[4], wsum[4];
    if (lane == 0) wm[w] = mx;
    __syncthreads();
    float gmax = fmaxf(fmaxf(wm[0], wm[1]), fmaxf(wm[2], wm[3]));
    float c = my_sum * __expf(my_max - gmax);
#pragma unroll
    for (int off = 1; off < 64; off <<= 1) c += __shfl_xor(c, off, 64);
    if (lane == 0) wsum[w] = c;
    __syncthreads();
    if (tid == 0) {
        float gs = wsum[0] + wsum[1] + wsum[2] + wsum[3];
        rstat[row * 2]     = gmax;
        rstat[row * 2 + 1] = 1.0f / gs;
    }
}

// ---------------- K4: recompute dots, write normalized softmax ------------------------
__global__ __launch_bounds__(256) void k4_out(const float* __restrict__ memT,
                                              const float* __restrict__ qT,
                                              const float* __restrict__ rstat,
                                              float* __restrict__ out) {
    __shared__ float qs[LL * MROWS];       // [l][r], 4 KB
    __shared__ float rs[MROWS * 2];
    int bx = blockIdx.x;
    int mtile = bx >> 6, rg = bx & 63;
    int r0 = rg * MROWS;
    int tid = threadIdx.x;
    int m = mtile * MTILE + tid * 4;
    stage_q(qT, r0, qs, tid);
    if (tid < MROWS * 2) rs[tid] = rstat[r0 * 2 + tid];
    __syncthreads();
    const float* mp = memT + m;
    float acc[MROWS][4];
#pragma unroll
    for (int r = 0; r < MROWS; ++r)
        acc[r][0] = acc[r][1] = acc[r][2] = acc[r][3] = 0.f;
#pragma unroll 4
    for (int l = 0; l < LL; ++l) {
        float4 v = *(const float4*)(mp + (size_t)l * MM);
        const f4v* qrow = (const f4v*)(qs + l * MROWS);
#pragma unroll
        for (int rq = 0; rq < MROWS / 4; ++rq) {
            f4v q4 = qrow[rq];             // ds_read_b128, broadcast
#pragma unroll
            for (int j = 0; j < 4; ++j) {
                int r = rq * 4 + j;
                float qv = q4[j];
                acc[r][0] = fmaf(qv, v.x, acc[r][0]);
                acc[r][1] = fmaf(qv, v.y, acc[r][1]);
                acc[r][2] = fmaf(qv, v.z, acc[r][2]);
                acc[r][3] = fmaf(qv, v.w, acc[r][3]);
            }
        }
    }
#pragma unroll
    for (int r = 0; r < MROWS; ++r) {
        float gmax = rs[r * 2];
        float gin  = rs[r * 2 + 1];
        f4v o;
        o.x = __expf(acc[r][0] - gmax) * gin;
        o.y = __expf(acc[r][1] - gmax) * gin;
        o.z = __expf(acc[r][2] - gmax) * gin;
        o.w = __expf(acc[r][3] - gmax) * gin;
        __builtin_nontemporal_store(o, (f4v*)(out + (size_t)(r0 + r) * MM + m));
    }
}

extern "C" void kernel_launch(void* const* d_in, const int* in_sizes, int n_in,
                              void* d_out, int out_size, void* d_ws, size_t ws_size,
                              hipStream_t stream) {
    const float* S   = (const float*)d_in[0];  // [256][2048]
    const float* mem = (const float*)d_in[1];  // [65536][64]
    const float* Wk  = (const float*)d_in[2];  // [256][2048]
    const float* bk  = (const float*)d_in[3];  // [256]
    const float* Wb  = (const float*)d_in[4];  // [4][2048]
    const float* bb  = (const float*)d_in[5];  // [4]
    float* out = (float*)d_out;                // [1024][65536]

    // workspace layout (floats), total ~23.3 MB
    float* w0    = (float*)d_ws;
    float* memT  = w0;                                   // 64*65536
    float* WkT   = memT  + (size_t)LL * MM;              // 2048*256
    float* kpart = WkT   + (size_t)RR * KEYS;            // 8*256*256
    float* qT    = kpart + (size_t)8 * BB * KEYS;        // 64*1024
    float* pmax  = qT    + (size_t)LL * NROW;            // 1024*256
    float* psum  = pmax  + (size_t)NROW * 256;           // 1024*256
    float* rstat = psum  + (size_t)NROW * 256;           // 1024*2

    transpose_k<<<dim3(MM / 64, 1), 256, 0, stream>>>(mem, memT, MM, LL);
    transpose_k<<<dim3(BB / 64, RR / 64), 256, 0, stream>>>(Wk, WkT, KEYS, RR);
    k0_keys   <<<dim3(32, 8),  256, 0, stream>>>(S, WkT, kpart);
    k1_finalize<<<NROW,        256, 0, stream>>>(S, kpart, bk, Wb, bb, qT);
    k2_partial<<<64 * 64,      256, 0, stream>>>(memT, qT, pmax, psum);
    k3_combine<<<NROW,         256, 0, stream>>>(pmax, psum, rstat);
    k4_out    <<<64 * 64,      256, 0, stream>>>(memT, qT, rstat, out);
}

// Round 3
// 397.071 us; speedup vs baseline: 1.2743x; 1.2743x over previous
//
#include <hip/hip_runtime.h>
#include <hip/hip_bf16.h>

// Problem constants (B,R,M,L,H) = (256, 2048, 65536, 64, 4)
#define BB   256
#define RR   2048
#define MM   65536
#define LL   64
#define HH   4
#define NROW 1024      // B*H rows
#define KEYS 256       // H*L

typedef float f32x4 __attribute__((ext_vector_type(4)));
typedef short short8 __attribute__((ext_vector_type(8)));

#define MFMA(A,B,C) __builtin_amdgcn_mfma_f32_16x16x32_bf16((A),(B),(C),0,0,0)

// ---- bf16 round-nearest-even split helpers ----
__device__ __forceinline__ unsigned short bf16_rn(float x) {
    union { float f; unsigned int u; } v; v.f = x;
    unsigned int r = v.u + 0x7FFFu + ((v.u >> 16) & 1u);
    return (unsigned short)(r >> 16);
}
__device__ __forceinline__ float bf16_to_f(unsigned short h) {
    union { float f; unsigned int u; } v; v.u = ((unsigned int)h) << 16; return v.f;
}
__device__ __forceinline__ void split8_store(const float* x, unsigned short* hi, unsigned short* lo) {
    unsigned int ph[4], pl[4];
#pragma unroll
    for (int j = 0; j < 4; ++j) {
        unsigned short h0 = bf16_rn(x[2*j]),   l0 = bf16_rn(x[2*j]   - bf16_to_f(h0));
        unsigned short h1 = bf16_rn(x[2*j+1]), l1 = bf16_rn(x[2*j+1] - bf16_to_f(h1));
        ph[j] = (unsigned int)h0 | ((unsigned int)h1 << 16);
        pl[j] = (unsigned int)l0 | ((unsigned int)l1 << 16);
    }
    ((uint4*)hi)[0] = make_uint4(ph[0], ph[1], ph[2], ph[3]);
    ((uint4*)lo)[0] = make_uint4(pl[0], pl[1], pl[2], pl[3]);
}

// ---------------- generic 64x64 tiled transpose: out[c][r] = in[r][c] ----------------
__global__ __launch_bounds__(256) void transpose_k(const float* __restrict__ in,
                                                   float* __restrict__ out,
                                                   int NR, int NC) {
    __shared__ float t[64 * 65];
    int r0 = blockIdx.x * 64, c0 = blockIdx.y * 64;
    int lane = threadIdx.x & 63, w = threadIdx.x >> 6;
#pragma unroll
    for (int i = 0; i < 16; ++i) {
        int rr = i * 4 + w;
        t[lane * 65 + rr] = in[(size_t)(r0 + rr) * NC + c0 + lane];
    }
    __syncthreads();
#pragma unroll
    for (int i = 0; i < 16; ++i) {
        int cc = i * 4 + w;
        out[(size_t)(c0 + cc) * NR + r0 + lane] = t[cc * 65 + lane];
    }
}

// ---------------- per-row max squared-norm of memory, block partials ----------------
__global__ __launch_bounds__(256) void normmax_k(const float* __restrict__ mem,
                                                 float* __restrict__ normpart) {
    int row = blockIdx.x * 256 + threadIdx.x;
    const float4* p = (const float4*)(mem + (size_t)row * LL);
    float s = 0.f;
#pragma unroll
    for (int i = 0; i < 16; ++i) { float4 v = p[i]; s += v.x*v.x + v.y*v.y + v.z*v.z + v.w*v.w; }
    int lane = threadIdx.x & 63, w = threadIdx.x >> 6;
#pragma unroll
    for (int off = 1; off < 64; off <<= 1) s = fmaxf(s, __shfl_xor(s, off, 64));
    __shared__ float sm[4];
    if (lane == 0) sm[w] = s;
    __syncthreads();
    if (threadIdx.x == 0)
        normpart[blockIdx.x] = fmaxf(fmaxf(sm[0], sm[1]), fmaxf(sm[2], sm[3]));
}

// ---------------- swizzle mem into MFMA B-fragment order, hi/lo bf16 ----------------
// frag_id = t*2 + c (t = m-tile 0..4095, c = K-chunk 0..1)
// bhi[(frag_id*64 + lane)*8 + j] = bf16( mem[t*16 + (lane&15)][c*32 + (lane>>4)*8 + j] )
__global__ __launch_bounds__(256) void prep_mem(const float* __restrict__ mem,
                                                unsigned short* __restrict__ bhi,
                                                unsigned short* __restrict__ blo) {
    int gid = blockIdx.x * 256 + threadIdx.x;   // 0..524287
    int lane = gid & 63, frag = gid >> 6;       // frag 0..8191
    int t = frag >> 1, c = frag & 1;
    int mrow = t * 16 + (lane & 15);
    int k0 = c * 32 + (lane >> 4) * 8;
    const float4* src = (const float4*)(mem + (size_t)mrow * LL + k0);
    float4 x0 = src[0], x1 = src[1];
    float x[8] = {x0.x, x0.y, x0.z, x0.w, x1.x, x1.y, x1.z, x1.w};
    split8_store(x, bhi + (size_t)gid * 8, blo + (size_t)gid * 8);
}

// ---------------- K0: split-k partial keys GEMM ----------------
__global__ __launch_bounds__(256) void k0_keys(const float* __restrict__ S,
                                               const float* __restrict__ WkT,
                                               float* __restrict__ kpart) {
    __shared__ float sl[8 * 256];
    int bg = blockIdx.x, kc = blockIdx.y, tid = threadIdx.x;
    int b0 = bg * 8;
#pragma unroll
    for (int bi = 0; bi < 8; ++bi)
        sl[bi * 256 + tid] = S[(size_t)(b0 + bi) * RR + kc * 256 + tid];
    __syncthreads();
    float acc[8] = {0,0,0,0,0,0,0,0};
    const float* wp = WkT + (size_t)kc * 256 * KEYS + tid;
#pragma unroll 4
    for (int kk = 0; kk < 256; ++kk) {
        float wv = wp[kk * KEYS];
#pragma unroll
        for (int bi = 0; bi < 8; ++bi)
            acc[bi] = fmaf(sl[bi * 256 + kk], wv, acc[bi]);
    }
    float* op = kpart + (size_t)kc * BB * KEYS + (size_t)b0 * KEYS + tid;
#pragma unroll
    for (int bi = 0; bi < 8; ++bi)
        op[bi * KEYS] = acc[bi];
}

// ---------------- K1: beta, key norm, q_rm[row][k] = keys*beta/norm, brow = beta*maxnorm ----
__global__ __launch_bounds__(256) void k1_finalize(const float* __restrict__ S,
                                                   const float* __restrict__ kpart,
                                                   const float* __restrict__ bk,
                                                   const float* __restrict__ Wb,
                                                   const float* __restrict__ bb,
                                                   const float* __restrict__ normpart,
                                                   float* __restrict__ q_rm,
                                                   float* __restrict__ brow) {
    int bh = blockIdx.x, b = bh >> 2, h = bh & 3;
    int tid = threadIdx.x, lane = tid & 63, w = tid >> 6;
    float p = 0.f;
#pragma unroll
    for (int i = 0; i < 8; ++i) {
        int k = i * 256 + tid;
        p += S[(size_t)b * RR + k] * Wb[(size_t)h * RR + k];
    }
    float nm = normpart[tid];
#pragma unroll
    for (int off = 1; off < 64; off <<= 1) {
        p  += __shfl_xor(p, off, 64);
        nm  = fmaxf(nm, __shfl_xor(nm, off, 64));
    }
    __shared__ float red[4], redm[4];
    if (lane == 0) { red[w] = p; redm[w] = nm; }
    __syncthreads();
    if (tid < 64) {
        float beta = red[0] + red[1] + red[2] + red[3] + bb[h];
        beta = fmaxf(beta, 0.f);
        float maxn = sqrtf(fmaxf(fmaxf(redm[0], redm[1]), fmaxf(redm[2], redm[3])));
        float kv = bk[h * LL + lane];
#pragma unroll
        for (int c = 0; c < 8; ++c)
            kv += kpart[(size_t)c * BB * KEYS + (size_t)b * KEYS + h * LL + lane];
        float sq = kv * kv;
#pragma unroll
        for (int off = 1; off < 64; off <<= 1) sq += __shfl_xor(sq, off, 64);
        float scale = beta / sqrtf(sq);
        q_rm[(size_t)bh * LL + lane] = kv * scale;
        if (lane == 0) brow[bh] = beta * maxn;   // exact upper bound on dot (Cauchy-Schwarz)
    }
}

// ---------------- swizzle q into MFMA A-fragment order, hi/lo bf16 ----------------
// frag_id = rtg*2 + c (rtg = 16-row tile 0..63)
__global__ __launch_bounds__(256) void prep_a(const float* __restrict__ q_rm,
                                              unsigned short* __restrict__ ahi,
                                              unsigned short* __restrict__ alo) {
    int gid = blockIdx.x * 256 + threadIdx.x;   // 0..8191
    int lane = gid & 63, frag = gid >> 6;       // frag 0..127
    int rtg = frag >> 1, c = frag & 1;
    int row = rtg * 16 + (lane & 15);
    int k0 = c * 32 + (lane >> 4) * 8;
    const float4* src = (const float4*)(q_rm + (size_t)row * LL + k0);
    float4 x0 = src[0], x1 = src[1];
    float x[8] = {x0.x, x0.y, x0.z, x0.w, x1.x, x1.y, x1.z, x1.w};
    split8_store(x, ahi + (size_t)gid * 8, alo + (size_t)gid * 8);
}

// ---------------- K2: split-bf16 MFMA dot + exp(d - brow) partial row sums ----------
// grid: 1024 blocks = 64 mblk (1024 m each) x 16 rg (64 rows each), rg fastest
__global__ __launch_bounds__(256) void k2_mfma(const unsigned short* __restrict__ bhi,
                                               const unsigned short* __restrict__ blo,
                                               const unsigned short* __restrict__ ahi,
                                               const unsigned short* __restrict__ alo,
                                               const float* __restrict__ brow,
                                               float* __restrict__ psum) {
    int bx = blockIdx.x;
    int mblk = bx >> 4, rg = bx & 15;
    int tid = threadIdx.x, w = tid >> 6, lane = tid & 63;
    int g = lane >> 4;
    short8 Ah[4][2], Al[4][2];
#pragma unroll
    for (int rt = 0; rt < 4; ++rt)
#pragma unroll
        for (int c = 0; c < 2; ++c) {
            size_t off = ((size_t)((rg * 4 + rt) * 2 + c) * 64 + lane) * 8;
            Ah[rt][c] = *(const short8*)(ahi + off);
            Al[rt][c] = *(const short8*)(alo + off);
        }
    float br[4][4];
#pragma unroll
    for (int rt = 0; rt < 4; ++rt)
#pragma unroll
        for (int r = 0; r < 4; ++r)
            br[rt][r] = brow[rg * 64 + rt * 16 + g * 4 + r];
    float s[4][4] = {{0.f}};
    int t0 = mblk * 64 + w * 16;
    for (int ti = 0; ti < 16; ++ti) {
        int t = t0 + ti;
        size_t o0 = ((size_t)(t * 2 + 0) * 64 + lane) * 8;
        size_t o1 = ((size_t)(t * 2 + 1) * 64 + lane) * 8;
        short8 Bh0 = *(const short8*)(bhi + o0);
        short8 Bh1 = *(const short8*)(bhi + o1);
        short8 Bl0 = *(const short8*)(blo + o0);
        short8 Bl1 = *(const short8*)(blo + o1);
#pragma unroll
        for (int rt = 0; rt < 4; ++rt) {
            f32x4 C = {0.f, 0.f, 0.f, 0.f};
            C = MFMA(Ah[rt][0], Bh0, C);
            C = MFMA(Ah[rt][1], Bh1, C);
            C = MFMA(Al[rt][0], Bh0, C);
            C = MFMA(Al[rt][1], Bh1, C);
            C = MFMA(Ah[rt][0], Bl0, C);
            C = MFMA(Ah[rt][1], Bl1, C);
#pragma unroll
            for (int r = 0; r < 4; ++r)
                s[rt][r] += __expf(C[r] - br[rt][r]);
        }
    }
#pragma unroll
    for (int rt = 0; rt < 4; ++rt)
#pragma unroll
        for (int r = 0; r < 4; ++r) {
            float v = s[rt][r];
            v += __shfl_xor(v, 1, 64);
            v += __shfl_xor(v, 2, 64);
            v += __shfl_xor(v, 4, 64);
            v += __shfl_xor(v, 8, 64);
            s[rt][r] = v;
        }
    if ((lane & 15) == 0) {
        int col = mblk * 4 + w;
#pragma unroll
        for (int rt = 0; rt < 4; ++rt)
#pragma unroll
            for (int r = 0; r < 4; ++r) {
                int row = rg * 64 + rt * 16 + g * 4 + r;
                psum[(size_t)row * 256 + col] = s[rt][r];
            }
    }
}

// ---------------- K3: combine 256 partial sums per row -> 1/sum ----------------
__global__ __launch_bounds__(256) void k3_combine(const float* __restrict__ psum,
                                                  float* __restrict__ ginv) {
    int row = blockIdx.x, tid = threadIdx.x, lane = tid & 63, w = tid >> 6;
    float v = psum[(size_t)row * 256 + tid];
#pragma unroll
    for (int off = 1; off < 64; off <<= 1) v += __shfl_xor(v, off, 64);
    __shared__ float sm[4];
    if (lane == 0) sm[w] = v;
    __syncthreads();
    if (tid == 0) ginv[row] = 1.0f / (sm[0] + sm[1] + sm[2] + sm[3]);
}

// ---------------- K4: recompute dots via MFMA, write exp(d-brow)*ginv ----------------
__global__ __launch_bounds__(256) void k4_mfma(const unsigned short* __restrict__ bhi,
                                               const unsigned short* __restrict__ blo,
                                               const unsigned short* __restrict__ ahi,
                                               const unsigned short* __restrict__ alo,
                                               const float* __restrict__ brow,
                                               const float* __restrict__ ginv,
                                               float* __restrict__ out) {
    int bx = blockIdx.x;
    int mblk = bx >> 4, rg = bx & 15;
    int tid = threadIdx.x, w = tid >> 6, lane = tid & 63;
    int g = lane >> 4;
    short8 Ah[4][2], Al[4][2];
#pragma unroll
    for (int rt = 0; rt < 4; ++rt)
#pragma unroll
        for (int c = 0; c < 2; ++c) {
            size_t off = ((size_t)((rg * 4 + rt) * 2 + c) * 64 + lane) * 8;
            Ah[rt][c] = *(const short8*)(ahi + off);
            Al[rt][c] = *(const short8*)(alo + off);
        }
    float br[4][4], gv[4][4];
    size_t rbase[4][4];
#pragma unroll
    for (int rt = 0; rt < 4; ++rt)
#pragma unroll
        for (int r = 0; r < 4; ++r) {
            int row = rg * 64 + rt * 16 + g * 4 + r;
            br[rt][r] = brow[row];
            gv[rt][r] = ginv[row];
            rbase[rt][r] = (size_t)row * MM + (lane & 15);
        }
    int t0 = mblk * 64 + w * 16;
    for (int ti = 0; ti < 16; ++ti) {
        int t = t0 + ti;
        size_t o0 = ((size_t)(t * 2 + 0) * 64 + lane) * 8;
        size_t o1 = ((size_t)(t * 2 + 1) * 64 + lane) * 8;
        short8 Bh0 = *(const short8*)(bhi + o0);
        short8 Bh1 = *(const short8*)(bhi + o1);
        short8 Bl0 = *(const short8*)(blo + o0);
        short8 Bl1 = *(const short8*)(blo + o1);
#pragma unroll
        for (int rt = 0; rt < 4; ++rt) {
            f32x4 C = {0.f, 0.f, 0.f, 0.f};
            C = MFMA(Ah[rt][0], Bh0, C);
            C = MFMA(Ah[rt][1], Bh1, C);
            C = MFMA(Al[rt][0], Bh0, C);
            C = MFMA(Al[rt][1], Bh1, C);
            C = MFMA(Ah[rt][0], Bl0, C);
            C = MFMA(Ah[rt][1], Bl1, C);
#pragma unroll
            for (int r = 0; r < 4; ++r) {
                float o = __expf(C[r] - br[rt][r]) * gv[rt][r];
                __builtin_nontemporal_store(o, out + rbase[rt][r] + (size_t)t * 16);
            }
        }
    }
}

extern "C" void kernel_launch(void* const* d_in, const int* in_sizes, int n_in,
                              void* d_out, int out_size, void* d_ws, size_t ws_size,
                              hipStream_t stream) {
    const float* S   = (const float*)d_in[0];  // [256][2048]
    const float* mem = (const float*)d_in[1];  // [65536][64]
    const float* Wk  = (const float*)d_in[2];  // [256][2048]
    const float* bk  = (const float*)d_in[3];  // [256]
    const float* Wb  = (const float*)d_in[4];  // [4][2048]
    const float* bb  = (const float*)d_in[5];  // [4]
    float* out = (float*)d_out;                // [1024][65536]

    // workspace layout (~21.5 MB, all segments 16B-aligned)
    float* WkT      = (float*)d_ws;                          // 2048*256
    float* kpart    = WkT   + (size_t)RR * KEYS;             // 8*256*256
    float* q_rm     = kpart + (size_t)8 * BB * KEYS;         // 1024*64
    float* psum     = q_rm  + (size_t)NROW * LL;             // 1024*256
    float* brow     = psum  + (size_t)NROW * 256;            // 1024
    float* ginv     = brow  + NROW;                          // 1024
    float* normpart = ginv  + NROW;                          // 256
    unsigned short* bhi = (unsigned short*)(normpart + 256); // 8192*512
    unsigned short* blo = bhi + (size_t)8192 * 512;
    unsigned short* ahi = blo + (size_t)8192 * 512;          // 128*512
    unsigned short* alo = ahi + (size_t)128 * 512;

    transpose_k<<<dim3(BB / 64, RR / 64), 256, 0, stream>>>(Wk, WkT, KEYS, RR);
    normmax_k  <<<256,         256, 0, stream>>>(mem, normpart);
    prep_mem   <<<2048,        256, 0, stream>>>(mem, bhi, blo);
    k0_keys    <<<dim3(32, 8), 256, 0, stream>>>(S, WkT, kpart);
    k1_finalize<<<NROW,        256, 0, stream>>>(S, kpart, bk, Wb, bb, normpart, q_rm, brow);
    prep_a     <<<32,          256, 0, stream>>>(q_rm, ahi, alo);
    k2_mfma    <<<1024,        256, 0, stream>>>(bhi, blo, ahi, alo, brow, psum);
    k3_combine <<<NROW,        256, 0, stream>>>(psum, ginv);
    k4_mfma    <<<1024,        256, 0, stream>>>(bhi, blo, ahi, alo, brow, ginv, out);
}